// Round 3
// baseline (155.044 us; speedup 1.0000x reference)
//
#include <hip/hip_runtime.h>
#include <math.h>

// Problem constants (fixed by reference)
#define NPAR 2048   // B*Kp
#define KP   1024
#define MM   8
#define CC   256
#define KC   8192   // Kp*M
#define NCH  16384  // B*Kc

// ws offsets (float units). Packed AoS float4 per parent:
//  PKL = {L10, L20, L21, logdet}
//  PKI = {i0,  i1,  i2,  L00}
//  PKM = {mx,  my,  mz,  L11}
#define WS_PKL    0        // [NPAR][4]
#define WS_PKI    8192     // [NPAR][4]
#define WS_PKM    16384    // [NPAR][4]
#define WS_L22    24576    // [NPAR]
#define WS_MEANSP 26624    // [NPAR]
#define WS_SUMSQ  28672    // [NPAR]
#define WS_DOT8   30720    // [NPAR][8]
#define WS_APRIOR 47104    // [NPAR]
#define WS_EGATE  49152    // [8][256]
#define WS_UGATE  51200    // [256]
#define WS_C0GATE 51456    // [256]
#define WS_GEO    51712    // [8][3]
#define WS_MEANE  51736    // [8]
#define WS_SUMSQE 51744    // [8]
#define WS_NEIGH  51752    // [NPAR] ints
#define WS_PGATE  53824    // [NPAR][256]
#define WS_GPART  578112   // [NPAR] per-parent g sums (kD -> kF)

// out offsets (float units)
#define OUT_S    0
#define OUT_MU   4194304
#define OUT_SIG  4243456
#define OUT_G    4390912
#define OUT_LOSS 4407296

__device__ __forceinline__ float siluf(float x){ return x / (1.f + expf(-x)); }
__device__ __forceinline__ float softplusf(float x){ return x > 20.f ? x : log1pf(expf(x)); }

// ================= Kernel A: 512-thread blocks for wave-parallelism =================
// blk 0..255   : batch-wide Cholesky into LDS + best-neighbor search (8 parents/block)
// blk 256..511 : gate-P GEMM, 8 rows/block (2 col-halves x 4 rows/thread) + row stats
// blk 512..767 : prior head, same shape
// blk 768      : E_gate
// blk 769      : u / c0
// blk 770      : geo offsets + emb stats
// 8 waves/block -> 16-24 waves/CU in GEMM phase (was 4: latency-bound, VALUBusy 31%).
__global__ __launch_bounds__(512) void kA(const float* __restrict__ sp,
                                          const float* __restrict__ mu_p,
                                          const float* __restrict__ Sig,
                                          const float* __restrict__ emb,
                                          const float* __restrict__ geom_W,
                                          const float* __restrict__ geom_b,
                                          const float* __restrict__ g_ln_g,
                                          const float* __restrict__ g_ln_b,
                                          const float* __restrict__ gW1,
                                          const float* __restrict__ gb1,
                                          const float* __restrict__ p_ln_g,
                                          const float* __restrict__ p_ln_b,
                                          const float* __restrict__ pW1,
                                          const float* __restrict__ pb1,
                                          const float* __restrict__ pW2,
                                          const float* __restrict__ pb2,
                                          float* __restrict__ ws) {
  // 40 KB: search blocks use SoA [10][1024]; GEMM blocks alias the front.
  __shared__ float smem[10 * 1024];
  int blk = blockIdx.x;
  int t = threadIdx.x;

  if (blk < 256) {
    // ---- fused Cholesky + neighbor search (8 parents per block) ----
    int b = blk >> 7;   // batch
#pragma unroll
    for (int q = 0; q < 2; q++) {
      int loc = q * 512 + t;        // local parent 0..1023
      int pid = b * KP + loc;       // global row
      const float* S = Sig + pid * 9;
      float a00 = S[0] + 1e-6f, a10 = S[3], a11 = S[4] + 1e-6f;
      float a20 = S[6], a21 = S[7], a22 = S[8] + 1e-6f;
      float L00 = sqrtf(a00); float i0 = 1.f / L00;
      float L10 = a10 * i0, L20 = a20 * i0;
      float L11 = sqrtf(a11 - L10 * L10); float i1 = 1.f / L11;
      float L21 = (a21 - L20 * L10) * i1;
      float L22 = sqrtf(a22 - L20 * L20 - L21 * L21); float i2 = 1.f / L22;
      float logdet = 2.f * logf(L00 * L11 * L22);
      float mx = mu_p[pid * 3 + 0], my = mu_p[pid * 3 + 1], mz = mu_p[pid * 3 + 2];
      smem[0 * 1024 + loc] = L10;
      smem[1 * 1024 + loc] = L20;
      smem[2 * 1024 + loc] = L21;
      smem[3 * 1024 + loc] = logdet;
      smem[4 * 1024 + loc] = i0;
      smem[5 * 1024 + loc] = i1;
      smem[6 * 1024 + loc] = i2;
      smem[7 * 1024 + loc] = mx;
      smem[8 * 1024 + loc] = my;
      smem[9 * 1024 + loc] = mz;
      // this block owns local parents (blk&127)*8..+7: write packed state for kD
      if ((loc >> 3) == (blk & 127)) {
        float4 pkl = {L10, L20, L21, logdet};
        float4 pki = {i0, i1, i2, L00};
        float4 pkm = {mx, my, mz, L11};
        *(float4*)(ws + WS_PKL + pid * 4) = pkl;
        *(float4*)(ws + WS_PKI + pid * 4) = pki;
        *(float4*)(ws + WS_PKM + pid * 4) = pkm;
        ws[WS_L22 + pid] = L22;
      }
    }
    __syncthreads();

    int wv = blk * 8 + (t >> 6);   // global parent row 0..2047
    int lane = t & 63;
    int j = wv & (KP - 1);
    float qx = smem[7 * 1024 + j], qy = smem[8 * 1024 + j], qz = smem[9 * 1024 + j];
    float best = -3.4e38f; int bidx = 1 << 30;
    for (int it = 0; it < 16; it++) {
      int k = it * 64 + lane;
      float dx = qx - smem[7 * 1024 + k];
      float dy = qy - smem[8 * 1024 + k];
      float dz = qz - smem[9 * 1024 + k];
      float y0 = dx * smem[4 * 1024 + k];
      float y1 = (dy - smem[0 * 1024 + k] * y0) * smem[5 * 1024 + k];
      float y2 = (dz - smem[1 * 1024 + k] * y0 - smem[2 * 1024 + k] * y1) * smem[6 * 1024 + k];
      float sc = -0.5f * (y0 * y0 + y1 * y1 + y2 * y2 + smem[3 * 1024 + k]);
      if (k == j) sc = -3.4e38f;
      if (sc > best || (sc == best && k < bidx)) { best = sc; bidx = k; }
    }
#pragma unroll
    for (int o = 32; o > 0; o >>= 1) {
      float ob = __shfl_xor(best, o);
      int   oi = __shfl_xor(bidx, o);
      if (ob > best || (ob == best && oi < bidx)) { best = ob; bidx = oi; }
    }
    if (lane == 0) ((int*)ws)[WS_NEIGH + wv] = bidx;
  } else {
    // ---- head GEMMs: 8 rows/block, 512 threads = 2 col-halves x 4 rows each ----
    float (*xs)[256] = (float(*)[256])smem;     // [8][256] = 2048
    float* statred   = smem + 2048;             // [8 waves][4 rows][10] = 320
    float* redS      = smem + 2368;             // [8][4]
    float* redQ      = smem + 2400;             // [8][4]
    float* mv0       = smem + 2432;             // [8]
    float* mv1       = smem + 2440;             // [8]
    float* redT      = smem + 2448;             // [8][4]

    int cblk = blk - 256;
    bool prior = (cblk >= 256 && cblk < 512);
    const float* W1 = prior ? pW1 : gW1;

    int col  = t & 255;
    int half = t >> 8;       // 0 or 1 -> rows half*4..half*4+3
    int wave = t >> 6;       // 0..7
    int lane = t & 63;
    int rbase = half * 4;

    if (cblk < 256) {
      // gate path: xs = sp*ln_g, plus row stats (mean/sumsq/dot8) for kD's LN
      int base = cblk * 8;
      float g = g_ln_g[col];
      float vr[4], em[8];
#pragma unroll
      for (int r = 0; r < 4; r++) vr[r] = sp[(base + rbase + r) * 256 + col];
#pragma unroll
      for (int m = 0; m < 8; m++) em[m] = emb[m * 256 + col];
#pragma unroll
      for (int r = 0; r < 4; r++) xs[rbase + r][col] = vr[r] * g;
#pragma unroll
      for (int r = 0; r < 4; r++) {
        float p0 = vr[r], p1 = vr[r] * vr[r];
        float d[8];
#pragma unroll
        for (int m = 0; m < 8; m++) d[m] = vr[r] * em[m];
#pragma unroll
        for (int o = 32; o > 0; o >>= 1) {
          p0 += __shfl_xor(p0, o);
          p1 += __shfl_xor(p1, o);
#pragma unroll
          for (int m = 0; m < 8; m++) d[m] += __shfl_xor(d[m], o);
        }
        if (lane == 0) {
          float* dst = statred + (wave * 4 + r) * 10;
          dst[0] = p0; dst[1] = p1;
#pragma unroll
          for (int m = 0; m < 8; m++) dst[2 + m] = d[m];
        }
      }
      __syncthreads();
      if (t < 8) {
        int R = t;                       // global row 0..7
        float s = 0.f, ss = 0.f, dd[8] = {0, 0, 0, 0, 0, 0, 0, 0};
#pragma unroll
        for (int q = 0; q < 4; q++) {
          float* srcp = statred + (((R >> 2) * 4 + q) * 4 + (R & 3)) * 10;
          s += srcp[0]; ss += srcp[1];
#pragma unroll
          for (int m = 0; m < 8; m++) dd[m] += srcp[2 + m];
        }
        ws[WS_MEANSP + base + R] = s * (1.f / 256.f);
        ws[WS_SUMSQ + base + R]  = ss;
#pragma unroll
        for (int m = 0; m < 8; m++) ws[WS_DOT8 + (base + R) * 8 + m] = dd[m];
      }
    } else if (cblk < 512) {
      int base = (cblk - 256) * 8;
      float vr[4], s1[4], s2[4];
#pragma unroll
      for (int r = 0; r < 4; r++) {
        vr[r] = sp[(base + rbase + r) * 256 + col];
        s1[r] = vr[r];
        s2[r] = vr[r] * vr[r];
      }
#pragma unroll
      for (int o = 32; o > 0; o >>= 1) {
#pragma unroll
        for (int r = 0; r < 4; r++) { s1[r] += __shfl_xor(s1[r], o); s2[r] += __shfl_xor(s2[r], o); }
      }
      if (lane == 0) {
#pragma unroll
        for (int r = 0; r < 4; r++) { redS[wave * 4 + r] = s1[r]; redQ[wave * 4 + r] = s2[r]; }
      }
      __syncthreads();
      if (t < 8) {
        int R = t;
        float sum = 0.f, sq = 0.f;
#pragma unroll
        for (int q = 0; q < 4; q++) {
          int idx = ((R >> 2) * 4 + q) * 4 + (R & 3);
          sum += redS[idx]; sq += redQ[idx];
        }
        float mean = sum * (1.f / 256.f);
        float var  = sq * (1.f / 256.f) - mean * mean;
        mv0[R] = mean;
        mv1[R] = rsqrtf(var + 1e-5f);
      }
      __syncthreads();
      float pg = p_ln_g[col], pbv = p_ln_b[col];
#pragma unroll
      for (int r = 0; r < 4; r++)
        xs[rbase + r][col] = (vr[r] - mv0[rbase + r]) * mv1[rbase + r] * pg + pbv;
    } else if (cblk == 512) {
      float g = g_ln_g[col];
#pragma unroll
      for (int r = 0; r < 4; r++) xs[rbase + r][col] = emb[(rbase + r) * 256 + col] * g;
    } else if (cblk == 513) {
      if (half == 0) {
        xs[0][col] = g_ln_g[col];
        xs[1][col] = g_ln_b[col];
        xs[2][col] = 0.f;
        xs[3][col] = 0.f;
      } else {
#pragma unroll
        for (int r = 0; r < 4; r++) xs[rbase + r][col] = 0.f;
      }
    } else {
      // cblk == 514: geo offsets + emb stats (threads >= 256 idle)
      if (t < 192) {
        int o = t >> 3, lane8 = t & 7;
        int m = o / 3, d = o % 3;
        float acc = 0.f;
        for (int k = lane8; k < 256; k += 8) acc += emb[m * 256 + k] * geom_W[k * 3 + d];
        acc += __shfl_xor(acc, 1); acc += __shfl_xor(acc, 2); acc += __shfl_xor(acc, 4);
        if (lane8 == 0) ws[WS_GEO + o] = acc + geom_b[d];
      } else if (t < 256) {
        int o = (t - 192) >> 3, lane8 = t & 7;
        if (o < 8) {
          float s = 0.f, ss = 0.f;
          for (int k = lane8; k < 256; k += 8) { float e = emb[o * 256 + k]; s += e; ss += e * e; }
          s  += __shfl_xor(s, 1);  s  += __shfl_xor(s, 2);  s  += __shfl_xor(s, 4);
          ss += __shfl_xor(ss, 1); ss += __shfl_xor(ss, 2); ss += __shfl_xor(ss, 4);
          if (lane8 == 0) { ws[WS_MEANE + o] = s * (1.f / 256.f); ws[WS_SUMSQE + o] = ss; }
        }
      }
      return;
    }
    __syncthreads();

    // k-unrolled x4: broadcast LDS reads for xs, coalesced global loads for W1.
    // 4 rows/thread; both col-halves issue the same W1 lines (L1-absorbed).
    float acc[4] = {0.f, 0.f, 0.f, 0.f};
    for (int k4 = 0; k4 < 256; k4 += 4) {
      float w0 = W1[(k4 + 0) * 256 + col];
      float w1 = W1[(k4 + 1) * 256 + col];
      float w2 = W1[(k4 + 2) * 256 + col];
      float w3 = W1[(k4 + 3) * 256 + col];
#pragma unroll
      for (int r = 0; r < 4; r++) {
        float4 x4 = *(const float4*)&xs[rbase + r][k4];
        acc[r] += x4.x * w0 + x4.y * w1 + x4.z * w2 + x4.w * w3;
      }
    }

    if (cblk < 256) {
      int base = cblk * 8;
#pragma unroll
      for (int r = 0; r < 4; r++) ws[WS_PGATE + (base + rbase + r) * 256 + col] = acc[r];
    } else if (cblk < 512) {
      int base = (cblk - 256) * 8;
      float b1 = pb1[col], w2 = pW2[col];
      float tv[4];
#pragma unroll
      for (int r = 0; r < 4; r++) {
        float h = acc[r] + b1;
        tv[r] = siluf(h) * w2;
      }
#pragma unroll
      for (int o = 32; o > 0; o >>= 1) {
#pragma unroll
        for (int r = 0; r < 4; r++) tv[r] += __shfl_xor(tv[r], o);
      }
      if (lane == 0) {
#pragma unroll
        for (int r = 0; r < 4; r++) redT[wave * 4 + r] = tv[r];
      }
      __syncthreads();
      if (t < 8) {
        int R = t;
        float sum = pb2[0];
#pragma unroll
        for (int q = 0; q < 4; q++) sum += redT[((R >> 2) * 4 + q) * 4 + (R & 3)];
        ws[WS_APRIOR + base + R] = softplusf(sum);
      }
    } else if (cblk == 512) {
#pragma unroll
      for (int r = 0; r < 4; r++) ws[WS_EGATE + (rbase + r) * 256 + col] = acc[r];
    } else {
      if (half == 0) {
        ws[WS_UGATE + col]  = acc[0];
        ws[WS_C0GATE + col] = acc[1] + gb1[col];
      }
    }
  }
}

// ================= Kernel D: one block per parent, wave handles 2 children =================
// All parent-level loads shared across the wave's 2 children in registers.
// NO device-scope atomics / fences here (round 3: per-block __threadfence
// across non-coherent XCD L2s serialized the kernel, 142 us vs ~12 us).
__global__ __launch_bounds__(256) void kD(const float* __restrict__ sp,
                                          const float* __restrict__ Sig,
                                          const float* __restrict__ mask,
                                          const float* __restrict__ xi_noise,
                                          const float* __restrict__ gW2,
                                          const float* __restrict__ gb2,
                                          float* __restrict__ ws,
                                          float* __restrict__ out) {
  __shared__ float gpart[8];
  int prow = blockIdx.x;            // parent 0..2047
  int wave = threadIdx.x >> 6;
  int lane = threadIdx.x & 63;
  int b = prow >> 10;
  int c4 = lane * 4;

  // ---- parent-shared loads ----
  float mean_sp = ws[WS_MEANSP + prow];
  float sumsq   = ws[WS_SUMSQ + prow];
  float aP      = ws[WS_APRIOR + prow];
  float lgA     = gb2[0] + 0.5f * logf(aP + 1e-8f);
  float mk      = mask[prow];

  const float4 plP = *(const float4*)(ws + WS_PKL + prow * 4);  // L10,L20,L21,ld
  const float4 piP = *(const float4*)(ws + WS_PKI + prow * 4);  // i0,i1,i2,L00
  const float4 pmP = *(const float4*)(ws + WS_PKM + prow * 4);  // mx,my,mz,L11
  float L22 = ws[WS_L22 + prow];

  int n1 = __builtin_amdgcn_readfirstlane(((const int*)ws)[WS_NEIGH + prow]);
  int nrow1 = b * KP + n1;
  const float4 plN = *(const float4*)(ws + WS_PKL + nrow1 * 4);
  const float4 piN = *(const float4*)(ws + WS_PKI + nrow1 * 4);
  const float4 pmN = *(const float4*)(ws + WS_PKM + nrow1 * 4);

  float Pv[4], Uv[4], C0v[4], W2v[4], s0v[4], s1v[4];
  *(float4*)Pv  = *(const float4*)(ws + WS_PGATE + prow * 256 + c4);
  *(float4*)Uv  = *(const float4*)(ws + WS_UGATE + c4);
  *(float4*)C0v = *(const float4*)(ws + WS_C0GATE + c4);
  *(float4*)W2v = *(const float4*)(gW2 + c4);
  *(float4*)s0v = *(const float4*)(sp + prow * 256 + c4);
  *(float4*)s1v = *(const float4*)(sp + nrow1 * 256 + c4);

  const float* S0 = Sig + prow * 9;
  const float* S1 = Sig + nrow1 * 9;
  float S0r[9], S1r[9];
#pragma unroll
  for (int q = 0; q < 9; q++) { S0r[q] = S0[q]; S1r[q] = S1[q]; }
  const float PHIm2 = 0.390625f; // 1.6^-2

#pragma unroll
  for (int c = 0; c < 2; c++) {
    int m  = wave * 2 + c;        // child slot 0..7
    int wv = prow * 8 + m;        // global child (KC == 8*KP)

    // --- LN stats for gate_in row ---
    float mean_x = mean_sp + ws[WS_MEANE + m];
    float Ex2 = sumsq + 2.f * ws[WS_DOT8 + prow * 8 + m] + ws[WS_SUMSQE + m];
    float var = Ex2 * (1.f / 256.f) - mean_x * mean_x;
    float rstd = rsqrtf(var + 1e-5f);

    // --- gate head epilogue ---
    float Ev[4];
    *(float4*)Ev = *(const float4*)(ws + WS_EGATE + m * 256 + c4);
    float partial = 0.f;
#pragma unroll
    for (int q = 0; q < 4; q++) {
      float pre = (Pv[q] + Ev[q] - mean_x * Uv[q]) * rstd + C0v[q];
      partial += siluf(pre) * W2v[q];
    }
#pragma unroll
    for (int o = 32; o > 0; o >>= 1) partial += __shfl_xor(partial, o);
    float bval = partial + lgA;
    float g = (1.f / (1.f + expf(-bval))) * mk;
    if (lane == 0) gpart[m] = g;

    // --- mu0 = mu_p + Lp @ (xi_noise + geo[m]) ---
    int xbase = (prow * 8 + m) * 3;
    float x0 = xi_noise[xbase + 0] + ws[WS_GEO + m * 3 + 0];
    float x1 = xi_noise[xbase + 1] + ws[WS_GEO + m * 3 + 1];
    float x2 = xi_noise[xbase + 2] + ws[WS_GEO + m * 3 + 2];
    float m0x = pmP.x + piP.w * x0;
    float m0y = pmP.y + plP.x * x0 + pmP.w * x1;
    float m0z = pmP.z + plP.y * x0 + plP.z * x1 + L22 * x2;

    // --- overlap scores: r0 = self, r1 = best neighbor ---
    float sc0, sc1;
    {
      float dx = m0x - pmP.x, dy = m0y - pmP.y, dz = m0z - pmP.z;
      float y0 = dx * piP.x;
      float y1 = (dy - plP.x * y0) * piP.y;
      float y2 = (dz - plP.y * y0 - plP.z * y1) * piP.z;
      sc0 = -0.5f * (y0*y0 + y1*y1 + y2*y2 + plP.w);
    }
    {
      float dx = m0x - pmN.x, dy = m0y - pmN.y, dz = m0z - pmN.z;
      float y0 = dx * piN.x;
      float y1 = (dy - plN.x * y0) * piN.y;
      float y2 = (dz - plN.y * y0 - plN.z * y1) * piN.z;
      sc1 = -0.5f * (y0*y0 + y1*y1 + y2*y2 + plN.w);
    }
    float mxs = fmaxf(sc0, sc1);
    float e0 = expf(sc0 - mxs), e1 = expf(sc1 - mxs);
    float inv = 1.f / (e0 + e1);
    float w0 = e0 * inv, w1 = e1 * inv;

    float mcx = w0 * pmP.x + w1 * pmN.x;
    float mcy = w0 * pmP.y + w1 * pmN.y;
    float mcz = w0 * pmP.z + w1 * pmN.z;

    // --- Sigma_child ---
    float dd0[3] = {pmP.x - mcx, pmP.y - mcy, pmP.z - mcz};
    float dd1[3] = {pmN.x - mcx, pmN.y - mcy, pmN.z - mcz};
    float Sout[9];
#pragma unroll
    for (int a = 0; a < 3; a++)
#pragma unroll
      for (int e = 0; e < 3; e++) {
        float v = (w0 * S0r[a*3+e] + w1 * S1r[a*3+e]) * PHIm2
                + w0 * dd0[a] * dd0[e] + w1 * dd1[a] * dd1[e];
        if (a == e) v += 1e-4f;
        Sout[a*3+e] = v;
      }

    if (lane == 0) {
      float* om = out + OUT_MU + wv * 3;
      om[0] = mcx; om[1] = mcy; om[2] = mcz;
      out[OUT_G + wv] = g;
      float* os = out + OUT_SIG + wv * 9;
#pragma unroll
      for (int q = 0; q < 9; q++) os[q] = Sout[q];
    }

    // --- s_child0 row: g * (w0*s_self + w1*s_nei) ---
    float gw0 = g * w0, gw1 = g * w1;
    float ov[4];
#pragma unroll
    for (int q = 0; q < 4; q++) ov[q] = gw0 * s0v[q] + gw1 * s1v[q];
    *(float4*)(out + OUT_S + wv * 256 + c4) = *(float4*)ov;
  }

  __syncthreads();
  if (threadIdx.x == 0) {
    float s = gpart[0] + gpart[1] + gpart[2] + gpart[3]
            + gpart[4] + gpart[5] + gpart[6] + gpart[7];
    ws[WS_GPART + prow] = s;
  }
}

// ================= Kernel F: loss_count (reads kD's per-parent partials, 8 KB) =================
__global__ __launch_bounds__(256) void kF(const float* __restrict__ ws,
                                          const int* __restrict__ Kt,
                                          float* __restrict__ out) {
  __shared__ float red[4][2];
  int t = threadIdx.x;
  const float* gp = ws + WS_GPART;
  float s0 = 0.f, s1 = 0.f;
#pragma unroll
  for (int it = 0; it < 4; it++) {
    s0 += gp[it * 256 + t];          // parents 0..1023  = batch 0
    s1 += gp[1024 + it * 256 + t];   // parents 1024..2047 = batch 1
  }
#pragma unroll
  for (int o = 32; o > 0; o >>= 1) {
    s0 += __shfl_xor(s0, o);
    s1 += __shfl_xor(s1, o);
  }
  int wave = t >> 6;
  if ((t & 63) == 0) { red[wave][0] = s0; red[wave][1] = s1; }
  __syncthreads();
  if (t == 0) {
    float S0 = red[0][0] + red[1][0] + red[2][0] + red[3][0];
    float S1 = red[0][1] + red[1][1] + red[2][1] + red[3][1];
    float K = (float)Kt[0];
    float l0 = S0 - K, l1 = S1 - K;
    out[OUT_LOSS] = 0.5f * (l0 * l0 + l1 * l1);
  }
}

extern "C" void kernel_launch(void* const* d_in, const int* in_sizes, int n_in,
                              void* d_out, int out_size, void* d_ws, size_t ws_size,
                              hipStream_t stream) {
  const float* s_parent   = (const float*)d_in[0];
  const float* mu_p       = (const float*)d_in[1];
  const float* Sigma_p    = (const float*)d_in[2];
  const float* mask_par   = (const float*)d_in[3];
  const float* xi_noise   = (const float*)d_in[4];
  const float* emb        = (const float*)d_in[5];
  const float* gate_ln_g  = (const float*)d_in[6];
  const float* gate_ln_b  = (const float*)d_in[7];
  const float* gate_W1    = (const float*)d_in[8];
  const float* gate_b1    = (const float*)d_in[9];
  const float* gate_W2    = (const float*)d_in[10];
  const float* gate_b2    = (const float*)d_in[11];
  const float* prior_ln_g = (const float*)d_in[12];
  const float* prior_ln_b = (const float*)d_in[13];
  const float* prior_W1   = (const float*)d_in[14];
  const float* prior_b1   = (const float*)d_in[15];
  const float* prior_W2   = (const float*)d_in[16];
  const float* prior_b2   = (const float*)d_in[17];
  const float* geom_W     = (const float*)d_in[18];
  const float* geom_b     = (const float*)d_in[19];
  const int*   K_target   = (const int*)d_in[20];

  float* ws  = (float*)d_ws;
  float* out = (float*)d_out;

  kA<<<771, 512, 0, stream>>>(s_parent, mu_p, Sigma_p, emb, geom_W, geom_b,
                              gate_ln_g, gate_ln_b, gate_W1, gate_b1,
                              prior_ln_g, prior_ln_b, prior_W1, prior_b1,
                              prior_W2, prior_b2, ws);
  kD<<<NPAR, 256, 0, stream>>>(s_parent, Sigma_p, mask_par, xi_noise,
                               gate_W2, gate_b2, ws, out);
  kF<<<1, 256, 0, stream>>>(ws, K_target, out);
}

// Round 4
// 142.424 us; speedup vs baseline: 1.0886x; 1.0886x over previous
//
#include <hip/hip_runtime.h>
#include <math.h>

// Problem constants (fixed by reference)
#define NPAR 2048   // B*Kp
#define KP   1024
#define MM   8
#define CC   256
#define KC   8192   // Kp*M
#define NCH  16384  // B*Kc

// ws offsets (float units). Packed AoS float4 per parent:
//  PKL = {L10, L20, L21, logdet}
//  PKI = {i0,  i1,  i2,  L00}
//  PKM = {mx,  my,  mz,  L11}
#define WS_PKL    0        // [NPAR][4]
#define WS_PKI    8192     // [NPAR][4]
#define WS_PKM    16384    // [NPAR][4]
#define WS_L22    24576    // [NPAR]
#define WS_MEANSP 26624    // [NPAR]
#define WS_SUMSQ  28672    // [NPAR]
#define WS_DOT8   30720    // [NPAR][8]
#define WS_APRIOR 47104    // [NPAR]
#define WS_EGATE  49152    // [8][256]
#define WS_UGATE  51200    // [256]
#define WS_C0GATE 51456    // [256]
#define WS_GEO    51712    // [8][3]
#define WS_MEANE  51736    // [8]
#define WS_SUMSQE 51744    // [8]
#define WS_NEIGH  51752    // [NPAR] ints
#define WS_PGATE  53824    // [NPAR][256]
#define WS_GPART  578112   // [4096] per-kD-block g partial sums

// out offsets (float units)
#define OUT_S    0
#define OUT_MU   4194304
#define OUT_SIG  4243456
#define OUT_G    4390912
#define OUT_LOSS 4407296

__device__ __forceinline__ float siluf(float x){ return x / (1.f + expf(-x)); }
__device__ __forceinline__ float softplusf(float x){ return x > 20.f ? x : log1pf(expf(x)); }

// ================= Kernel A: fused (chol + neighbor search) | (stats + head GEMMs) | geo =================
// blk 0..511    : batch-wide Cholesky into LDS (redundant per block, Sigma is L2-resident)
//                 + best-neighbor search from LDS (conflict-free SoA)
//                 + write packed PK to ws for this block's own 4 parents (for kD)
// blk 512..767  : gate-P GEMM (8 rows) + fused row stats (mean/sumsq/dot8) for kD's LN
// blk 768..1023 : prior head (unchanged)
// blk 1024      : E_gate
// blk 1025      : u / c0
// blk 1026      : geo offsets + emb stats
__global__ __launch_bounds__(256) void kA(const float* __restrict__ sp,
                                          const float* __restrict__ mu_p,
                                          const float* __restrict__ Sig,
                                          const float* __restrict__ emb,
                                          const float* __restrict__ geom_W,
                                          const float* __restrict__ geom_b,
                                          const float* __restrict__ g_ln_g,
                                          const float* __restrict__ g_ln_b,
                                          const float* __restrict__ gW1,
                                          const float* __restrict__ gb1,
                                          const float* __restrict__ p_ln_g,
                                          const float* __restrict__ p_ln_b,
                                          const float* __restrict__ pW1,
                                          const float* __restrict__ pb1,
                                          const float* __restrict__ pW2,
                                          const float* __restrict__ pb2,
                                          float* __restrict__ ws) {
  // 40 KB: search blocks use SoA [10][1024]; GEMM blocks alias the front.
  __shared__ float smem[10 * 1024];
  int blk = blockIdx.x;
  int t = threadIdx.x;

  if (blk < 512) {
    // ---- fused Cholesky + neighbor search ----
    int b = blk >> 8;   // batch
#pragma unroll
    for (int q = 0; q < 4; q++) {
      int loc = q * 256 + t;        // local parent 0..1023
      int pid = b * KP + loc;       // global row
      const float* S = Sig + pid * 9;
      float a00 = S[0] + 1e-6f, a10 = S[3], a11 = S[4] + 1e-6f;
      float a20 = S[6], a21 = S[7], a22 = S[8] + 1e-6f;
      float L00 = sqrtf(a00); float i0 = 1.f / L00;
      float L10 = a10 * i0, L20 = a20 * i0;
      float L11 = sqrtf(a11 - L10 * L10); float i1 = 1.f / L11;
      float L21 = (a21 - L20 * L10) * i1;
      float L22 = sqrtf(a22 - L20 * L20 - L21 * L21); float i2 = 1.f / L22;
      float logdet = 2.f * logf(L00 * L11 * L22);
      float mx = mu_p[pid * 3 + 0], my = mu_p[pid * 3 + 1], mz = mu_p[pid * 3 + 2];
      smem[0 * 1024 + loc] = L10;
      smem[1 * 1024 + loc] = L20;
      smem[2 * 1024 + loc] = L21;
      smem[3 * 1024 + loc] = logdet;
      smem[4 * 1024 + loc] = i0;
      smem[5 * 1024 + loc] = i1;
      smem[6 * 1024 + loc] = i2;
      smem[7 * 1024 + loc] = mx;
      smem[8 * 1024 + loc] = my;
      smem[9 * 1024 + loc] = mz;
      // this block owns parents blk*4..blk*4+3: write packed state for kD
      if ((loc >> 2) == (blk & 255)) {
        float4 pkl = {L10, L20, L21, logdet};
        float4 pki = {i0, i1, i2, L00};
        float4 pkm = {mx, my, mz, L11};
        *(float4*)(ws + WS_PKL + pid * 4) = pkl;
        *(float4*)(ws + WS_PKI + pid * 4) = pki;
        *(float4*)(ws + WS_PKM + pid * 4) = pkm;
        ws[WS_L22 + pid] = L22;
      }
    }
    __syncthreads();

    int wv = blk * 4 + (t >> 6);   // global parent row 0..2047
    int lane = t & 63;
    int j = wv & (KP - 1);
    float qx = smem[7 * 1024 + j], qy = smem[8 * 1024 + j], qz = smem[9 * 1024 + j];
    float best = -3.4e38f; int bidx = 1 << 30;
    for (int it = 0; it < 16; it++) {
      int k = it * 64 + lane;
      float dx = qx - smem[7 * 1024 + k];
      float dy = qy - smem[8 * 1024 + k];
      float dz = qz - smem[9 * 1024 + k];
      float y0 = dx * smem[4 * 1024 + k];
      float y1 = (dy - smem[0 * 1024 + k] * y0) * smem[5 * 1024 + k];
      float y2 = (dz - smem[1 * 1024 + k] * y0 - smem[2 * 1024 + k] * y1) * smem[6 * 1024 + k];
      float sc = -0.5f * (y0 * y0 + y1 * y1 + y2 * y2 + smem[3 * 1024 + k]);
      if (k == j) sc = -3.4e38f;
      if (sc > best || (sc == best && k < bidx)) { best = sc; bidx = k; }
    }
#pragma unroll
    for (int o = 32; o > 0; o >>= 1) {
      float ob = __shfl_xor(best, o);
      int   oi = __shfl_xor(bidx, o);
      if (ob > best || (ob == best && oi < bidx)) { best = ob; bidx = oi; }
    }
    if (lane == 0) ((int*)ws)[WS_NEIGH + wv] = bidx;
  } else {
    // ---- head GEMMs (+ fused stats on the gate path) ----
    float (*xs)[256] = (float(*)[256])smem;          // [8][256]
    float* statred   = smem + 2048;                  // [4][8][10] = 320
    float (*redS)[8] = (float(*)[8])(smem + 2432);
    float (*redQ)[8] = (float(*)[8])(smem + 2464);
    float (*mv)[8]   = (float(*)[8])(smem + 2496);
    float (*red)[8]  = (float(*)[8])(smem + 2528);

    int cblk = blk - 512;
    bool prior = (cblk >= 256 && cblk < 512);
    const float* W1 = prior ? pW1 : gW1;

    if (cblk < 256) {
      // gate path: xs = sp*ln_g, plus row stats for kD's LN
      int base = cblk * 8;
      float g = g_ln_g[t];
      float vr[8], em[8];
#pragma unroll
      for (int r = 0; r < 8; r++) vr[r] = sp[(base + r) * 256 + t];
#pragma unroll
      for (int m = 0; m < 8; m++) em[m] = emb[m * 256 + t];
#pragma unroll
      for (int r = 0; r < 8; r++) xs[r][t] = vr[r] * g;
      int wave = t >> 6, lane = t & 63;
#pragma unroll
      for (int r = 0; r < 8; r++) {
        float p0 = vr[r], p1 = vr[r] * vr[r];
        float d[8];
#pragma unroll
        for (int m = 0; m < 8; m++) d[m] = vr[r] * em[m];
#pragma unroll
        for (int o = 32; o > 0; o >>= 1) {
          p0 += __shfl_xor(p0, o);
          p1 += __shfl_xor(p1, o);
#pragma unroll
          for (int m = 0; m < 8; m++) d[m] += __shfl_xor(d[m], o);
        }
        if (lane == 0) {
          float* dst = statred + (wave * 8 + r) * 10;
          dst[0] = p0; dst[1] = p1;
#pragma unroll
          for (int m = 0; m < 8; m++) dst[2 + m] = d[m];
        }
      }
      __syncthreads();
      if (t < 8) {
        int r = t;
        float s = 0.f, ss = 0.f, dd[8] = {0, 0, 0, 0, 0, 0, 0, 0};
#pragma unroll
        for (int w = 0; w < 4; w++) {
          float* srcp = statred + (w * 8 + r) * 10;
          s += srcp[0]; ss += srcp[1];
#pragma unroll
          for (int m = 0; m < 8; m++) dd[m] += srcp[2 + m];
        }
        ws[WS_MEANSP + base + r] = s * (1.f / 256.f);
        ws[WS_SUMSQ + base + r]  = ss;
#pragma unroll
        for (int m = 0; m < 8; m++) ws[WS_DOT8 + (base + r) * 8 + m] = dd[m];
      }
    } else if (cblk < 512) {
      int base = (cblk - 256) * 8;
      float vr[8], s1[8], s2[8];
#pragma unroll
      for (int r = 0; r < 8; r++) {
        vr[r] = sp[(base + r) * 256 + t];
        s1[r] = vr[r];
        s2[r] = vr[r] * vr[r];
      }
#pragma unroll
      for (int o = 32; o > 0; o >>= 1) {
#pragma unroll
        for (int r = 0; r < 8; r++) { s1[r] += __shfl_xor(s1[r], o); s2[r] += __shfl_xor(s2[r], o); }
      }
      int wave = t >> 6;
      if ((t & 63) == 0) {
#pragma unroll
        for (int r = 0; r < 8; r++) { redS[wave][r] = s1[r]; redQ[wave][r] = s2[r]; }
      }
      __syncthreads();
      if (t < 8) {
        float sum = redS[0][t] + redS[1][t] + redS[2][t] + redS[3][t];
        float sq  = redQ[0][t] + redQ[1][t] + redQ[2][t] + redQ[3][t];
        float mean = sum * (1.f / 256.f);
        float var  = sq * (1.f / 256.f) - mean * mean;
        mv[0][t] = mean;
        mv[1][t] = rsqrtf(var + 1e-5f);
      }
      __syncthreads();
      float pg = p_ln_g[t], pbv = p_ln_b[t];
#pragma unroll
      for (int r = 0; r < 8; r++)
        xs[r][t] = (vr[r] - mv[0][r]) * mv[1][r] * pg + pbv;
    } else if (cblk == 512) {
      float g = g_ln_g[t];
#pragma unroll
      for (int r = 0; r < 8; r++) xs[r][t] = emb[r * 256 + t] * g;
    } else if (cblk == 513) {
      xs[0][t] = g_ln_g[t];
      xs[1][t] = g_ln_b[t];
#pragma unroll
      for (int r = 2; r < 8; r++) xs[r][t] = 0.f;
    } else {
      // cblk == 514: geo offsets + emb stats (no GEMM for this block)
      if (t < 192) {
        int o = t >> 3, lane8 = t & 7;
        int m = o / 3, d = o % 3;
        float acc = 0.f;
        for (int k = lane8; k < 256; k += 8) acc += emb[m * 256 + k] * geom_W[k * 3 + d];
        acc += __shfl_xor(acc, 1); acc += __shfl_xor(acc, 2); acc += __shfl_xor(acc, 4);
        if (lane8 == 0) ws[WS_GEO + o] = acc + geom_b[d];
      } else {
        int o = (t - 192) >> 3, lane8 = t & 7;
        if (o < 8) {
          float s = 0.f, ss = 0.f;
          for (int k = lane8; k < 256; k += 8) { float e = emb[o * 256 + k]; s += e; ss += e * e; }
          s  += __shfl_xor(s, 1);  s  += __shfl_xor(s, 2);  s  += __shfl_xor(s, 4);
          ss += __shfl_xor(ss, 1); ss += __shfl_xor(ss, 2); ss += __shfl_xor(ss, 4);
          if (lane8 == 0) { ws[WS_MEANE + o] = s * (1.f / 256.f); ws[WS_SUMSQE + o] = ss; }
        }
      }
      return;
    }
    __syncthreads();

    // k-unrolled x4: broadcast LDS reads for xs, 4 coalesced global loads for W1
    float acc[8] = {0,0,0,0,0,0,0,0};
    for (int k4 = 0; k4 < 256; k4 += 4) {
      float w0 = W1[(k4+0) * 256 + t];
      float w1 = W1[(k4+1) * 256 + t];
      float w2 = W1[(k4+2) * 256 + t];
      float w3 = W1[(k4+3) * 256 + t];
#pragma unroll
      for (int r = 0; r < 8; r++) {
        float4 x4 = *(const float4*)&xs[r][k4];
        acc[r] += x4.x * w0 + x4.y * w1 + x4.z * w2 + x4.w * w3;
      }
    }

    if (cblk < 256) {
      int base = cblk * 8;
#pragma unroll
      for (int r = 0; r < 8; r++) ws[WS_PGATE + (base + r) * 256 + t] = acc[r];
    } else if (cblk < 512) {
      int base = (cblk - 256) * 8;
      float b1 = pb1[t], w2 = pW2[t];
      float tv[8];
#pragma unroll
      for (int r = 0; r < 8; r++) {
        float h = acc[r] + b1;
        tv[r] = siluf(h) * w2;
      }
#pragma unroll
      for (int o = 32; o > 0; o >>= 1) {
#pragma unroll
        for (int r = 0; r < 8; r++) tv[r] += __shfl_xor(tv[r], o);
      }
      int wave = t >> 6;
      if ((t & 63) == 0) {
#pragma unroll
        for (int r = 0; r < 8; r++) red[wave][r] = tv[r];
      }
      __syncthreads();
      if (t < 8) {
        float sum = red[0][t] + red[1][t] + red[2][t] + red[3][t] + pb2[0];
        ws[WS_APRIOR + base + t] = softplusf(sum);
      }
    } else if (cblk == 512) {
#pragma unroll
      for (int r = 0; r < 8; r++) ws[WS_EGATE + r * 256 + t] = acc[r];
    } else {
      ws[WS_UGATE + t]  = acc[0];
      ws[WS_C0GATE + t] = acc[1] + gb1[t];
    }
  }
}

// ================= Kernel D: per-child everything (one wave per child) =================
// NO device-scope atomics / fences here (round 3: per-block __threadfence
// across non-coherent XCD L2s serialized the kernel, 142 us vs ~12 us).
// Adds per-block g partial sums (LDS-only reduction) so kF reads 16 KB not 64 KB.
__global__ __launch_bounds__(256) void kD(const float* __restrict__ sp,
                                          const float* __restrict__ Sig,
                                          const float* __restrict__ mask,
                                          const float* __restrict__ xi_noise,
                                          const float* __restrict__ gW2,
                                          const float* __restrict__ gb2,
                                          float* __restrict__ ws,
                                          float* __restrict__ out) {
  __shared__ float gpart[4];
  int wv   = blockIdx.x * 4 + (threadIdx.x >> 6);  // child 0..16383 (= b*Kc+i)
  int lane = threadIdx.x & 63;
  int b = wv >> 13;
  int i = wv & (KC - 1);
  int j = i >> 3;
  int m = i & 7;
  int prow = b * KP + j;

  // --- LN stats for gate_in row ---
  float mean_x = ws[WS_MEANSP + prow] + ws[WS_MEANE + m];
  float Ex2 = ws[WS_SUMSQ + prow] + 2.f * ws[WS_DOT8 + prow * 8 + m] + ws[WS_SUMSQE + m];
  float var = Ex2 * (1.f / 256.f) - mean_x * mean_x;
  float rstd = rsqrtf(var + 1e-5f);

  // --- gate head epilogue: pre = (P + E - mean*u)*rstd + c0; silu; dot W2 ---
  int c4 = lane * 4;
  float Pv[4], Ev[4], Uv[4], C0v[4], W2v[4];
  *(float4*)Pv  = *(const float4*)(ws + WS_PGATE + prow * 256 + c4);
  *(float4*)Ev  = *(const float4*)(ws + WS_EGATE + m * 256 + c4);
  *(float4*)Uv  = *(const float4*)(ws + WS_UGATE + c4);
  *(float4*)C0v = *(const float4*)(ws + WS_C0GATE + c4);
  *(float4*)W2v = *(const float4*)(gW2 + c4);
  float partial = 0.f;
#pragma unroll
  for (int q = 0; q < 4; q++) {
    float pre = (Pv[q] + Ev[q] - mean_x * Uv[q]) * rstd + C0v[q];
    partial += siluf(pre) * W2v[q];
  }
#pragma unroll
  for (int o = 32; o > 0; o >>= 1) partial += __shfl_xor(partial, o);
  float aP = ws[WS_APRIOR + prow];
  float bval = partial + gb2[0] + 0.5f * logf(aP + 1e-8f);
  float g = (1.f / (1.f + expf(-bval))) * mask[prow];

  // per-block g partial (children of one block are same batch: 4 | 8192)
  if (lane == 0) gpart[threadIdx.x >> 6] = g;
  __syncthreads();
  if (threadIdx.x == 0)
    ws[WS_GPART + blockIdx.x] = gpart[0] + gpart[1] + gpart[2] + gpart[3];

  // --- parent packed state ---
  const float4 plP = *(const float4*)(ws + WS_PKL + prow * 4);  // L10,L20,L21,ld
  const float4 piP = *(const float4*)(ws + WS_PKI + prow * 4);  // i0,i1,i2,L00
  const float4 pmP = *(const float4*)(ws + WS_PKM + prow * 4);  // mx,my,mz,L11
  float L22 = ws[WS_L22 + prow];

  // --- mu0 = mu_p + Lp @ (xi_noise + geo[m]) ---
  int xbase = (prow * 8 + m) * 3;
  float x0 = xi_noise[xbase + 0] + ws[WS_GEO + m * 3 + 0];
  float x1 = xi_noise[xbase + 1] + ws[WS_GEO + m * 3 + 1];
  float x2 = xi_noise[xbase + 2] + ws[WS_GEO + m * 3 + 2];
  float m0x = pmP.x + piP.w * x0;
  float m0y = pmP.y + plP.x * x0 + pmP.w * x1;
  float m0z = pmP.z + plP.y * x0 + plP.z * x1 + L22 * x2;

  // --- neighbors: r0 = self, r1 = precomputed best ---
  int n1 = ((const int*)ws)[WS_NEIGH + prow];
  int nrow1 = b * KP + n1;
  const float4 plN = *(const float4*)(ws + WS_PKL + nrow1 * 4);
  const float4 piN = *(const float4*)(ws + WS_PKI + nrow1 * 4);
  const float4 pmN = *(const float4*)(ws + WS_PKM + nrow1 * 4);

  float sc[2], nx[2], ny[2], nz[2];
  {
    float dx = m0x - pmP.x, dy = m0y - pmP.y, dz = m0z - pmP.z;
    float y0 = dx * piP.x;
    float y1 = (dy - plP.x * y0) * piP.y;
    float y2 = (dz - plP.y * y0 - plP.z * y1) * piP.z;
    sc[0] = -0.5f * (y0*y0 + y1*y1 + y2*y2 + plP.w);
    nx[0] = pmP.x; ny[0] = pmP.y; nz[0] = pmP.z;
  }
  {
    float dx = m0x - pmN.x, dy = m0y - pmN.y, dz = m0z - pmN.z;
    float y0 = dx * piN.x;
    float y1 = (dy - plN.x * y0) * piN.y;
    float y2 = (dz - plN.y * y0 - plN.z * y1) * piN.z;
    sc[1] = -0.5f * (y0*y0 + y1*y1 + y2*y2 + plN.w);
    nx[1] = pmN.x; ny[1] = pmN.y; nz[1] = pmN.z;
  }
  float mxs = fmaxf(sc[0], sc[1]);
  float e0 = expf(sc[0] - mxs), e1 = expf(sc[1] - mxs);
  float inv = 1.f / (e0 + e1);
  float w0 = e0 * inv, w1 = e1 * inv;

  float mcx = w0 * nx[0] + w1 * nx[1];
  float mcy = w0 * ny[0] + w1 * ny[1];
  float mcz = w0 * nz[0] + w1 * nz[1];

  // --- Sigma_child ---
  float d0x = nx[0] - mcx, d0y = ny[0] - mcy, d0z = nz[0] - mcz;
  float d1x = nx[1] - mcx, d1y = ny[1] - mcy, d1z = nz[1] - mcz;
  const float* S0 = Sig + prow * 9;
  const float* S1 = Sig + nrow1 * 9;
  const float PHIm2 = 0.390625f; // 1.6^-2
  float Sout[9];
  float dd0[3] = {d0x, d0y, d0z};
  float dd1[3] = {d1x, d1y, d1z};
#pragma unroll
  for (int a = 0; a < 3; a++)
#pragma unroll
    for (int e = 0; e < 3; e++) {
      float v = (w0 * S0[a*3+e] + w1 * S1[a*3+e]) * PHIm2
              + w0 * dd0[a] * dd0[e] + w1 * dd1[a] * dd1[e];
      if (a == e) v += 1e-4f;
      Sout[a*3+e] = v;
    }

  if (lane == 0) {
    float* om = out + OUT_MU + wv * 3;
    om[0] = mcx; om[1] = mcy; om[2] = mcz;
    out[OUT_G + wv] = g;
    float* os = out + OUT_SIG + wv * 9;
#pragma unroll
    for (int q = 0; q < 9; q++) os[q] = Sout[q];
  }

  // --- s_child0 row: g * (w0*s_self + w1*s_nei) ---
  float s0v[4], s1v[4], ov[4];
  *(float4*)s0v = *(const float4*)(sp + prow * 256 + c4);
  *(float4*)s1v = *(const float4*)(sp + nrow1 * 256 + c4);
  float gw0 = g * w0, gw1 = g * w1;
#pragma unroll
  for (int q = 0; q < 4; q++) ov[q] = gw0 * s0v[q] + gw1 * s1v[q];
  *(float4*)(out + OUT_S + wv * 256 + c4) = *(float4*)ov;
}

// ================= Kernel F: loss_count (reads kD's per-block partials, 16 KB) =================
__global__ __launch_bounds__(256) void kF(const float* __restrict__ ws,
                                          const int* __restrict__ Kt,
                                          float* __restrict__ out) {
  __shared__ float red[4][2];
  int t = threadIdx.x;
  const float* gp = ws + WS_GPART;
  float s0 = 0.f, s1 = 0.f;
#pragma unroll
  for (int it = 0; it < 8; it++) {
    s0 += gp[it * 256 + t];          // blocks 0..2047  = batch 0
    s1 += gp[2048 + it * 256 + t];   // blocks 2048..4095 = batch 1
  }
#pragma unroll
  for (int o = 32; o > 0; o >>= 1) {
    s0 += __shfl_xor(s0, o);
    s1 += __shfl_xor(s1, o);
  }
  int wave = t >> 6;
  if ((t & 63) == 0) { red[wave][0] = s0; red[wave][1] = s1; }
  __syncthreads();
  if (t == 0) {
    float S0 = red[0][0] + red[1][0] + red[2][0] + red[3][0];
    float S1 = red[0][1] + red[1][1] + red[2][1] + red[3][1];
    float K = (float)Kt[0];
    float l0 = S0 - K, l1 = S1 - K;
    out[OUT_LOSS] = 0.5f * (l0 * l0 + l1 * l1);
  }
}

extern "C" void kernel_launch(void* const* d_in, const int* in_sizes, int n_in,
                              void* d_out, int out_size, void* d_ws, size_t ws_size,
                              hipStream_t stream) {
  const float* s_parent   = (const float*)d_in[0];
  const float* mu_p       = (const float*)d_in[1];
  const float* Sigma_p    = (const float*)d_in[2];
  const float* mask_par   = (const float*)d_in[3];
  const float* xi_noise   = (const float*)d_in[4];
  const float* emb        = (const float*)d_in[5];
  const float* gate_ln_g  = (const float*)d_in[6];
  const float* gate_ln_b  = (const float*)d_in[7];
  const float* gate_W1    = (const float*)d_in[8];
  const float* gate_b1    = (const float*)d_in[9];
  const float* gate_W2    = (const float*)d_in[10];
  const float* gate_b2    = (const float*)d_in[11];
  const float* prior_ln_g = (const float*)d_in[12];
  const float* prior_ln_b = (const float*)d_in[13];
  const float* prior_W1   = (const float*)d_in[14];
  const float* prior_b1   = (const float*)d_in[15];
  const float* prior_W2   = (const float*)d_in[16];
  const float* prior_b2   = (const float*)d_in[17];
  const float* geom_W     = (const float*)d_in[18];
  const float* geom_b     = (const float*)d_in[19];
  const int*   K_target   = (const int*)d_in[20];

  float* ws  = (float*)d_ws;
  float* out = (float*)d_out;

  kA<<<1027, 256, 0, stream>>>(s_parent, mu_p, Sigma_p, emb, geom_W, geom_b,
                               gate_ln_g, gate_ln_b, gate_W1, gate_b1,
                               prior_ln_g, prior_ln_b, prior_W1, prior_b1,
                               prior_W2, prior_b2, ws);
  kD<<<NCH / 4, 256, 0, stream>>>(s_parent, Sigma_p, mask_par, xi_noise,
                                  gate_W2, gate_b2, ws, out);
  kF<<<1, 256, 0, stream>>>(ws, K_target, out);
}